// Round 1
// baseline (332.688 us; speedup 1.0000x reference)
//
#include <hip/hip_runtime.h>

// VMD (Variational Mode Decomposition) for x: (16, 8192, 4) f32.
// B=16, C=4, T=8192, T2=16384, K=4, ALPHA=2000, TAU=0, 20 iterations.
// TAU=0 => lam == 0 forever. Negative-frequency half stays 0 => iterate only
// on 8192 positive bins per channel.

#define N2        16384
#define HALF      8192
#define LOGN      14
#define NTHREADS  1024
#define KMODES    4
#define NITERS    20
#define ALPHA_F   2000.0f
#define TWO_PI    6.28318530717958647692f

__device__ __forceinline__ unsigned bitrev14(unsigned x) { return __brev(x) >> 18; }

// ---------------------------------------------------------------------------
// Kernel 1: per-channel forward FFT of mirror-extended signal + 20 VMD iters.
// One block per channel (ch = b*4 + c), 1024 threads, 8 bins/thread.
// ---------------------------------------------------------------------------
__global__ __launch_bounds__(NTHREADS) void vmd_forward_iter(
    const float* __restrict__ x, float2* __restrict__ ws_u,
    float* __restrict__ ws_omega)
{
    __shared__ float2 A[N2];   // 128 KB (gfx950: 160 KB LDS/WG)
    const int tid = threadIdx.x;
    const int ch  = blockIdx.x;          // b*4 + c
    const int b   = ch >> 2, c = ch & 3;
    const float* xb = x + (size_t)b * 8192 * 4 + c;   // x[b, t, c], stride 4 in t

    // Mirror-extend: f[0:4096]=x[4095..0], f[4096:12288]=x[0..8191],
    // f[12288:16384]=x[8191..4096]
    for (int i = tid; i < N2; i += NTHREADS) {
        int t;
        if (i < 4096)       t = 4095 - i;
        else if (i < 12288) t = i - 4096;
        else                t = 20479 - i;
        A[i] = make_float2(xb[(size_t)t * 4], 0.0f);
    }
    __syncthreads();

    // Forward FFT: radix-2 DIF in place; position p ends up holding X[bitrev(p)].
    for (int s = 0; s < LOGN; ++s) {
        const int   half    = (N2 >> 1) >> s;           // 8192 .. 1
        const float inv_len = (float)(1 << s) / (float)N2;  // 1/len
        #pragma unroll
        for (int u = 0; u < 8; ++u) {
            int t   = tid + u * NTHREADS;               // butterfly id 0..8191
            int j   = t & (half - 1);
            int blk = t >> (13 - s);
            int i0  = blk * (half << 1) + j;
            int i1  = i0 + half;
            float2 a  = A[i0];
            float2 bb = A[i1];
            float dx = a.x - bb.x, dy = a.y - bb.y;
            float ang = -TWO_PI * ((float)j * inv_len);
            float sn, cs;
            __sincosf(ang, &sn, &cs);                   // w = e^{-2*pi*i*j/len}
            A[i0] = make_float2(a.x + bb.x, a.y + bb.y);
            A[i1] = make_float2(dx * cs - dy * sn, dx * sn + dy * cs);
        }
        __syncthreads();
    }

    // Read my 8 positive bins j = tid + u*1024 (F[j] sits at bitrev14(j)).
    float2 F[8];
    #pragma unroll
    for (int u = 0; u < 8; ++u) {
        int j = tid + u * NTHREADS;
        F[u] = A[bitrev14((unsigned)j)];
    }
    __syncthreads();   // LDS now reusable as reduction scratch

    float2 S[8];
    float2 U[KMODES][8];
    #pragma unroll
    for (int u = 0; u < 8; ++u) {
        S[u] = make_float2(0.f, 0.f);
        #pragma unroll
        for (int k = 0; k < KMODES; ++k) U[k][u] = make_float2(0.f, 0.f);
    }
    float omg[KMODES] = {0.0f, 0.125f, 0.25f, 0.375f};   // 0.5*k/K

    float* red = (float*)A;   // [16 waves][8] partials + [128..131] omega bcast

    for (int it = 0; it < NITERS; ++it) {
        float num[KMODES], den[KMODES];
        #pragma unroll
        for (int k = 0; k < KMODES; ++k) {
            float nk = 0.f, dk = 0.f;
            const float ok = omg[k];
            #pragma unroll
            for (int u = 0; u < 8; ++u) {
                float fr  = (float)(tid + u * NTHREADS) * (1.0f / (float)N2);
                float d   = fr - ok;
                float dnm = fmaf(ALPHA_F * d, d, 1.0f);
                float rcp = __builtin_amdgcn_rcpf(dnm);
                // S holds full sum of modes; exclude mode k:
                float nr = F[u].x - (S[u].x - U[k][u].x);
                float ni = F[u].y - (S[u].y - U[k][u].y);
                float ur = nr * rcp, ui = ni * rcp;
                S[u].x += ur - U[k][u].x;
                S[u].y += ui - U[k][u].y;
                U[k][u].x = ur; U[k][u].y = ui;
                float p = fmaf(ur, ur, ui * ui);
                nk = fmaf(fr, p, nk);
                dk += p;
            }
            num[k] = nk; den[k] = dk;
        }
        // Batched block reduction of 8 scalars (num[4], den[4]).
        #pragma unroll
        for (int off = 32; off >= 1; off >>= 1) {
            #pragma unroll
            for (int m = 0; m < KMODES; ++m) {
                num[m] += __shfl_down(num[m], off);
                den[m] += __shfl_down(den[m], off);
            }
        }
        const int lane = tid & 63, wid = tid >> 6;
        if (lane == 0) {
            #pragma unroll
            for (int m = 0; m < KMODES; ++m) {
                red[wid * 8 + m]     = num[m];
                red[wid * 8 + 4 + m] = den[m];
            }
        }
        __syncthreads();
        if (tid < 16) {
            float v[8];
            #pragma unroll
            for (int m = 0; m < 8; ++m) v[m] = red[tid * 8 + m];
            #pragma unroll
            for (int off = 8; off >= 1; off >>= 1) {
                #pragma unroll
                for (int m = 0; m < 8; ++m) v[m] += __shfl_down(v[m], off);
            }
            if (tid == 0) {
                #pragma unroll
                for (int m = 0; m < KMODES; ++m) red[128 + m] = v[m] / v[4 + m];
            }
        }
        __syncthreads();
        #pragma unroll
        for (int m = 0; m < KMODES; ++m) omg[m] = red[128 + m];
        // no barrier needed: next writes touch red[0..127] only (disjoint)
    }

    // Write final positive-half u_hat and omega.
    #pragma unroll
    for (int k = 0; k < KMODES; ++k) {
        float2* dst = ws_u + (size_t)(ch * KMODES + k) * HALF;
        #pragma unroll
        for (int u = 0; u < 8; ++u) dst[tid + u * NTHREADS] = U[k][u];
    }
    if (tid < KMODES) ws_omega[ch * KMODES + tid] = omg[tid];
}

// ---------------------------------------------------------------------------
// Kernel 2: per (channel, mode) inverse FFT; keep real part of middle T samples.
// Spectrum in natural FFT order (derived from full/ifftshift in reference):
//   G[0] = conj(p[0]); G[j] = p[j] (1<=j<8192); G[8192] = conj(p[8191]);
//   G[16384-j] = conj(p[j]) (1<=j<8192).
// ---------------------------------------------------------------------------
__global__ __launch_bounds__(NTHREADS) void vmd_inverse(
    const float2* __restrict__ ws_u, float* __restrict__ out)
{
    __shared__ float2 A[N2];
    const int tid = threadIdx.x;
    const int bid = blockIdx.x;             // ch*4 + k
    const float2* pos = ws_u + (size_t)bid * HALF;

    for (int i = tid; i < HALF; i += NTHREADS) {
        float2 p = pos[i];
        if (i == 0) {
            A[0] = make_float2(p.x, -p.y);
        } else {
            A[i]      = p;
            A[N2 - i] = make_float2(p.x, -p.y);
        }
        if (i == HALF - 1) A[HALF] = make_float2(p.x, -p.y);
    }
    __syncthreads();

    // Inverse FFT: radix-2 DIF with e^{+i...}; output bit-reversed; scale 1/N.
    for (int s = 0; s < LOGN; ++s) {
        const int   half    = (N2 >> 1) >> s;
        const float inv_len = (float)(1 << s) / (float)N2;
        #pragma unroll
        for (int u = 0; u < 8; ++u) {
            int t   = tid + u * NTHREADS;
            int j   = t & (half - 1);
            int blk = t >> (13 - s);
            int i0  = blk * (half << 1) + j;
            int i1  = i0 + half;
            float2 a  = A[i0];
            float2 bb = A[i1];
            float dx = a.x - bb.x, dy = a.y - bb.y;
            float ang = TWO_PI * ((float)j * inv_len);
            float sn, cs;
            __sincosf(ang, &sn, &cs);
            A[i0] = make_float2(a.x + bb.x, a.y + bb.y);
            A[i1] = make_float2(dx * cs - dy * sn, dx * sn + dy * cs);
        }
        __syncthreads();
    }

    // u[b,k,t,c] = Re(ifft)[4096 + t] ; out index ((b*4+k)*8192 + t)*4 + c
    const int ch = bid >> 2, k = bid & 3;
    const int b  = ch >> 2,  c = ch & 3;
    float* outp = out + (size_t)(b * 4 + k) * 8192 * 4 + c;
    for (int i = tid; i < HALF; i += NTHREADS) {
        int n = 4096 + i;
        float v = A[bitrev14((unsigned)n)].x * (1.0f / (float)N2);
        outp[(size_t)i * 4] = v;
    }
}

// ---------------------------------------------------------------------------
// Kernel 3: omega_b[b,k] = mean_c omega[b,c,k]
// ---------------------------------------------------------------------------
__global__ void omega_mean(const float* __restrict__ ws_omega,
                           float* __restrict__ out_omega)
{
    int i = threadIdx.x;                 // b*4 + k, 64 total
    if (i < 64) {
        int b = i >> 2, k = i & 3;
        float s = 0.f;
        #pragma unroll
        for (int c = 0; c < 4; ++c) s += ws_omega[(b * 4 + c) * 4 + k];
        out_omega[i] = 0.25f * s;
    }
}

extern "C" void kernel_launch(void* const* d_in, const int* in_sizes, int n_in,
                              void* d_out, int out_size, void* d_ws, size_t ws_size,
                              hipStream_t stream)
{
    (void)in_sizes; (void)n_in; (void)out_size; (void)ws_size;
    const float* x = (const float*)d_in[0];
    float* out = (float*)d_out;

    float2* ws_u     = (float2*)d_ws;  // 64 ch * 4 modes * 8192 float2 = 16 MB
    float*  ws_omega = (float*)((char*)d_ws + (size_t)64 * 4 * HALF * sizeof(float2));

    vmd_forward_iter<<<64, NTHREADS, 0, stream>>>(x, ws_u, ws_omega);
    vmd_inverse<<<256, NTHREADS, 0, stream>>>(ws_u, out);
    omega_mean<<<1, 64, 0, stream>>>(ws_omega, out + 2097152);
}

// Round 2
// 207.292 us; speedup vs baseline: 1.6049x; 1.6049x over previous
//
#include <hip/hip_runtime.h>

// VMD (Variational Mode Decomposition) for x: (16, 8192, 4) f32.
// B=16, C=4, T=8192, T2=16384, K=4, ALPHA=2000, TAU=0, 20 iterations.
// TAU=0 => lam == 0 forever. Negative-frequency half stays 0 => iterate only
// on 8192 positive bins per channel.
//
// R2: kill scratch spill in vmd_forward_iter.
//  - State reduced 96->80 floats/thread: keep residual R = F - S instead of
//    F and S separately (num = R + U_k; R' = num - U_k_new).
//  - __launch_bounds__(1024,4): LDS (128KB) caps us at 1 block/CU = 4 waves/EU
//    anyway, so let the compiler use 128 VGPRs instead of 64 (R1 spilled:
//    WRITE_SIZE 39.7MB vs 16MB actual, VALUBusy 8%).

#define N2        16384
#define HALF      8192
#define LOGN      14
#define NTHREADS  1024
#define KMODES    4
#define NITERS    20
#define ALPHA_F   2000.0f
#define TWO_PI    6.28318530717958647692f

__device__ __forceinline__ unsigned bitrev14(unsigned x) { return __brev(x) >> 18; }

// ---------------------------------------------------------------------------
// Kernel 1: per-channel forward FFT of mirror-extended signal + 20 VMD iters.
// One block per channel (ch = b*4 + c), 1024 threads, 8 bins/thread.
// ---------------------------------------------------------------------------
__global__ __launch_bounds__(NTHREADS, 4) void vmd_forward_iter(
    const float* __restrict__ x, float2* __restrict__ ws_u,
    float* __restrict__ ws_omega)
{
    __shared__ float2 A[N2];   // 128 KB (gfx950: 160 KB LDS/WG)
    const int tid = threadIdx.x;
    const int ch  = blockIdx.x;          // b*4 + c
    const int b   = ch >> 2, c = ch & 3;
    const float* xb = x + (size_t)b * 8192 * 4 + c;   // x[b, t, c], stride 4 in t

    // Mirror-extend: f[0:4096]=x[4095..0], f[4096:12288]=x[0..8191],
    // f[12288:16384]=x[8191..4096]
    for (int i = tid; i < N2; i += NTHREADS) {
        int t;
        if (i < 4096)       t = 4095 - i;
        else if (i < 12288) t = i - 4096;
        else                t = 20479 - i;
        A[i] = make_float2(xb[(size_t)t * 4], 0.0f);
    }
    __syncthreads();

    // Forward FFT: radix-2 DIF in place; position p ends up holding X[bitrev(p)].
    for (int s = 0; s < LOGN; ++s) {
        const int   half    = (N2 >> 1) >> s;           // 8192 .. 1
        const float inv_len = (float)(1 << s) / (float)N2;  // 1/len
        #pragma unroll
        for (int u = 0; u < 8; ++u) {
            int t   = tid + u * NTHREADS;               // butterfly id 0..8191
            int j   = t & (half - 1);
            int blk = t >> (13 - s);
            int i0  = blk * (half << 1) + j;
            int i1  = i0 + half;
            float2 a  = A[i0];
            float2 bb = A[i1];
            float dx = a.x - bb.x, dy = a.y - bb.y;
            float ang = -TWO_PI * ((float)j * inv_len);
            float sn, cs;
            __sincosf(ang, &sn, &cs);                   // w = e^{-2*pi*i*j/len}
            A[i0] = make_float2(a.x + bb.x, a.y + bb.y);
            A[i1] = make_float2(dx * cs - dy * sn, dx * sn + dy * cs);
        }
        __syncthreads();
    }

    // Read my 8 positive bins j = tid + u*1024 (F[j] sits at bitrev14(j)).
    // R = F - S with S=0 initially, so R starts as F.
    float Rx[8], Ry[8];
    #pragma unroll
    for (int u = 0; u < 8; ++u) {
        int j = tid + u * NTHREADS;
        float2 f = A[bitrev14((unsigned)j)];
        Rx[u] = f.x; Ry[u] = f.y;
    }
    __syncthreads();   // LDS now reusable as reduction scratch

    float Ux[KMODES][8], Uy[KMODES][8];
    float fr[8];
    #pragma unroll
    for (int u = 0; u < 8; ++u) {
        fr[u] = (float)(tid + u * NTHREADS) * (1.0f / (float)N2);
        #pragma unroll
        for (int k = 0; k < KMODES; ++k) { Ux[k][u] = 0.f; Uy[k][u] = 0.f; }
    }
    float omg[KMODES] = {0.0f, 0.125f, 0.25f, 0.375f};   // 0.5*k/K

    float* red = (float*)A;   // [16 waves][8] partials + [128..131] omega bcast

    for (int it = 0; it < NITERS; ++it) {
        float num[KMODES], den[KMODES];
        #pragma unroll
        for (int k = 0; k < KMODES; ++k) {
            float nk = 0.f, dk = 0.f;
            const float ok = omg[k];
            #pragma unroll
            for (int u = 0; u < 8; ++u) {
                float d   = fr[u] - ok;
                float dnm = fmaf(ALPHA_F * d, d, 1.0f);
                float rcp = __builtin_amdgcn_rcpf(dnm);
                // numerator = F - (S - U_k) = R + U_k
                float nr = Rx[u] + Ux[k][u];
                float ni = Ry[u] + Uy[k][u];
                float ur = nr * rcp, ui = ni * rcp;
                // R' = F - S' = (R + U_k_old) - U_k_new = num - U_new
                Rx[u] = nr - ur;
                Ry[u] = ni - ui;
                Ux[k][u] = ur; Uy[k][u] = ui;
                float p = fmaf(ur, ur, ui * ui);
                nk = fmaf(fr[u], p, nk);
                dk += p;
            }
            num[k] = nk; den[k] = dk;
        }
        // Batched block reduction of 8 scalars (num[4], den[4]).
        #pragma unroll
        for (int off = 32; off >= 1; off >>= 1) {
            #pragma unroll
            for (int m = 0; m < KMODES; ++m) {
                num[m] += __shfl_down(num[m], off);
                den[m] += __shfl_down(den[m], off);
            }
        }
        const int lane = tid & 63, wid = tid >> 6;
        if (lane == 0) {
            #pragma unroll
            for (int m = 0; m < KMODES; ++m) {
                red[wid * 8 + m]     = num[m];
                red[wid * 8 + 4 + m] = den[m];
            }
        }
        __syncthreads();
        if (tid < 16) {
            float v[8];
            #pragma unroll
            for (int m = 0; m < 8; ++m) v[m] = red[tid * 8 + m];
            #pragma unroll
            for (int off = 8; off >= 1; off >>= 1) {
                #pragma unroll
                for (int m = 0; m < 8; ++m) v[m] += __shfl_down(v[m], off);
            }
            if (tid == 0) {
                #pragma unroll
                for (int m = 0; m < KMODES; ++m) red[128 + m] = v[m] / v[4 + m];
            }
        }
        __syncthreads();
        #pragma unroll
        for (int m = 0; m < KMODES; ++m) omg[m] = red[128 + m];
        // no barrier needed: next writes touch red[0..127] only (disjoint)
    }

    // Write final positive-half u_hat and omega.
    #pragma unroll
    for (int k = 0; k < KMODES; ++k) {
        float2* dst = ws_u + (size_t)(ch * KMODES + k) * HALF;
        #pragma unroll
        for (int u = 0; u < 8; ++u)
            dst[tid + u * NTHREADS] = make_float2(Ux[k][u], Uy[k][u]);
    }
    if (tid < KMODES) ws_omega[ch * KMODES + tid] = omg[tid];
}

// ---------------------------------------------------------------------------
// Kernel 2: per (channel, mode) inverse FFT; keep real part of middle T samples.
// Spectrum in natural FFT order (derived from full/ifftshift in reference):
//   G[0] = conj(p[0]); G[j] = p[j] (1<=j<8192); G[8192] = conj(p[8191]);
//   G[16384-j] = conj(p[j]) (1<=j<8192).
// ---------------------------------------------------------------------------
__global__ __launch_bounds__(NTHREADS) void vmd_inverse(
    const float2* __restrict__ ws_u, float* __restrict__ out)
{
    __shared__ float2 A[N2];
    const int tid = threadIdx.x;
    const int bid = blockIdx.x;             // ch*4 + k
    const float2* pos = ws_u + (size_t)bid * HALF;

    for (int i = tid; i < HALF; i += NTHREADS) {
        float2 p = pos[i];
        if (i == 0) {
            A[0] = make_float2(p.x, -p.y);
        } else {
            A[i]      = p;
            A[N2 - i] = make_float2(p.x, -p.y);
        }
        if (i == HALF - 1) A[HALF] = make_float2(p.x, -p.y);
    }
    __syncthreads();

    // Inverse FFT: radix-2 DIF with e^{+i...}; output bit-reversed; scale 1/N.
    for (int s = 0; s < LOGN; ++s) {
        const int   half    = (N2 >> 1) >> s;
        const float inv_len = (float)(1 << s) / (float)N2;
        #pragma unroll
        for (int u = 0; u < 8; ++u) {
            int t   = tid + u * NTHREADS;
            int j   = t & (half - 1);
            int blk = t >> (13 - s);
            int i0  = blk * (half << 1) + j;
            int i1  = i0 + half;
            float2 a  = A[i0];
            float2 bb = A[i1];
            float dx = a.x - bb.x, dy = a.y - bb.y;
            float ang = TWO_PI * ((float)j * inv_len);
            float sn, cs;
            __sincosf(ang, &sn, &cs);
            A[i0] = make_float2(a.x + bb.x, a.y + bb.y);
            A[i1] = make_float2(dx * cs - dy * sn, dx * sn + dy * cs);
        }
        __syncthreads();
    }

    // u[b,k,t,c] = Re(ifft)[4096 + t] ; out index ((b*4+k)*8192 + t)*4 + c
    const int ch = bid >> 2, k = bid & 3;
    const int b  = ch >> 2,  c = ch & 3;
    float* outp = out + (size_t)(b * 4 + k) * 8192 * 4 + c;
    for (int i = tid; i < HALF; i += NTHREADS) {
        int n = 4096 + i;
        float v = A[bitrev14((unsigned)n)].x * (1.0f / (float)N2);
        outp[(size_t)i * 4] = v;
    }
}

// ---------------------------------------------------------------------------
// Kernel 3: omega_b[b,k] = mean_c omega[b,c,k]
// ---------------------------------------------------------------------------
__global__ void omega_mean(const float* __restrict__ ws_omega,
                           float* __restrict__ out_omega)
{
    int i = threadIdx.x;                 // b*4 + k, 64 total
    if (i < 64) {
        int b = i >> 2, k = i & 3;
        float s = 0.f;
        #pragma unroll
        for (int c = 0; c < 4; ++c) s += ws_omega[(b * 4 + c) * 4 + k];
        out_omega[i] = 0.25f * s;
    }
}

extern "C" void kernel_launch(void* const* d_in, const int* in_sizes, int n_in,
                              void* d_out, int out_size, void* d_ws, size_t ws_size,
                              hipStream_t stream)
{
    (void)in_sizes; (void)n_in; (void)out_size; (void)ws_size;
    const float* x = (const float*)d_in[0];
    float* out = (float*)d_out;

    float2* ws_u     = (float2*)d_ws;  // 64 ch * 4 modes * 8192 float2 = 16 MB
    float*  ws_omega = (float*)((char*)d_ws + (size_t)64 * 4 * HALF * sizeof(float2));

    vmd_forward_iter<<<64, NTHREADS, 0, stream>>>(x, ws_u, ws_omega);
    vmd_inverse<<<256, NTHREADS, 0, stream>>>(ws_u, out);
    omega_mean<<<1, 64, 0, stream>>>(ws_omega, out + 2097152);
}